// Round 6
// baseline (279.837 us; speedup 1.0000x reference)
//
#include <hip/hip_runtime.h>
#include <cstdint>

static constexpr int M = 16384;   // B*N rows
static constexpr int D = 768;     // feature dim
static constexpr int E = 32;      // code dim
static constexpr int K = 8192;    // codebook size

typedef _Float16 half8 __attribute__((ext_vector_type(8)));
typedef float f32x4 __attribute__((ext_vector_type(4)));

// ---------------- Pre-pass: W1 [768k][768n] fp32 -> W1aT/W1bT [768n][768k] fp16 ----------------
__global__ __launch_bounds__(256) void split_w1t(const float* __restrict__ W1,
    _Float16* __restrict__ W1aT, _Float16* __restrict__ W1bT)
{
  __shared__ float tile[32][33];
  const int tx = threadIdx.x & 31, ty = threadIdx.x >> 5;
  const int kb = blockIdx.x * 32, nb = blockIdx.y * 32;
#pragma unroll
  for (int i = 0; i < 4; ++i)
    tile[ty * 4 + i][tx] = W1[(size_t)(kb + ty * 4 + i) * 768 + nb + tx];
  __syncthreads();
#pragma unroll
  for (int i = 0; i < 4; ++i) {
    const int n = nb + ty * 4 + i, k = kb + tx;
    const float v = tile[tx][ty * 4 + i] * 64.0f;
    const _Float16 h = (_Float16)v;
    W1aT[(size_t)n * 768 + k] = h;
    W1bT[(size_t)n * 768 + k] = (_Float16)((v - (float)h) * 4096.0f);
  }
}

// ---------------- Pre-pass: codebook -> cc norms + f16 hi/res split ----------------
__global__ __launch_bounds__(256) void cb_prep(const float* __restrict__ CB,
    float* __restrict__ cc, _Float16* __restrict__ CBh, _Float16* __restrict__ CBr)
{
  const int k = blockIdx.x * 256 + threadIdx.x;
  const float4* p = (const float4*)(CB + (size_t)k * E);
  _Float16 hb[32], rb[32];
  float s = 0.f;
#pragma unroll
  for (int q = 0; q < 8; ++q) {
    float4 v = p[q];
    const float e[4] = {v.x, v.y, v.z, v.w};
#pragma unroll
    for (int j = 0; j < 4; ++j) {
      s += e[j] * e[j];
      const _Float16 h = (_Float16)e[j];
      hb[q * 4 + j] = h;
      rb[q * 4 + j] = (_Float16)((e[j] - (float)h) * 4096.0f);
    }
  }
  cc[k] = s;
#pragma unroll
  for (int q = 0; q < 4; ++q) {
    *(half8*)(CBh + (size_t)k * E + q * 8) = *(half8*)&hb[q * 8];
    *(half8*)(CBr + (size_t)k * E + q * 8) = *(half8*)&rb[q * 8];
  }
}

// ---------------- Kernel A: H1 = tanh(X @ W1 + b1) via f16 MFMA split emulation ----------------
// 64x64 tile, BK=32, 4 waves of 32x32, padded LDS (stride 40 halves), 40KB -> 4 blocks/CU.
// Math (split constants, MFMA order, 24 K-steps) identical to round-5 kernel.
__global__ __launch_bounds__(256, 4) void gemm1_mfma(
    const float* __restrict__ X, const _Float16* __restrict__ Bag,
    const _Float16* __restrict__ Bbg, const float* __restrict__ bias,
    float* __restrict__ C)
{
  constexpr int RS = 40;   // LDS row stride in halves (80B: 16B-aligned, 2-way banks)
  __shared__ __align__(16) _Float16 Aa[2][64 * RS];
  __shared__ __align__(16) _Float16 Ab[2][64 * RS];
  __shared__ __align__(16) _Float16 Ba[2][64 * RS];
  __shared__ __align__(16) _Float16 Bb[2][64 * RS];

  const int t = threadIdx.x;
  const int lane = t & 63, wave = t >> 6;
  const int wm = wave >> 1, wn = wave & 1;
  const int rowBase = blockIdx.x * 64;
  const int colBase = blockIdx.y * 64;

  // staging map: thread -> (row ra, k-slot ka of 8 elems)
  const int ra = t >> 2, ka = (t & 3) * 8;
  const float*    Xp  = X   + (size_t)(rowBase + ra) * D + ka;
  const _Float16* BaP = Bag + (size_t)(colBase + ra) * D + ka;
  const _Float16* BbP = Bbg + (size_t)(colBase + ra) * D + ka;
  const int woff = ra * RS + ka;

  // fragment offsets (halves): row*(RS) + kgroup*8
  const int arow = wm * 32 + (lane & 15);
  const int brow = wn * 32 + (lane & 15);
  const int kg = (lane >> 4) * 8;

  f32x4 accM[2][2], accR[2][2];
  const f32x4 z4 = {0.f, 0.f, 0.f, 0.f};
#pragma unroll
  for (int i = 0; i < 2; ++i)
#pragma unroll
    for (int j = 0; j < 2; ++j) { accM[i][j] = z4; accR[i][j] = z4; }

  auto cvt8 = [](float4 pa, float4 pb, half8& hi, half8& re) {
    const float v[8] = {pa.x, pa.y, pa.z, pa.w, pb.x, pb.y, pb.z, pb.w};
#pragma unroll
    for (int e = 0; e < 8; ++e) {
      const _Float16 h = (_Float16)v[e];
      hi[e] = h;
      re[e] = (_Float16)((v[e] - (float)h) * 4096.0f);
    }
  };

  { // prologue: stage ks=0 into buffer 0
    float4 x0 = *(const float4*)Xp;
    float4 x1 = *(const float4*)(Xp + 4);
    half8 b0 = *(const half8*)BaP;
    half8 b1 = *(const half8*)BbP;
    half8 hi, re;
    cvt8(x0, x1, hi, re);
    *(half8*)&Aa[0][woff] = hi;
    *(half8*)&Ab[0][woff] = re;
    *(half8*)&Ba[0][woff] = b0;
    *(half8*)&Bb[0][woff] = b1;
    __syncthreads();
  }

  for (int ks = 0; ks < 24; ++ks) {
    const int cur = ks & 1, nxt = cur ^ 1;
    const bool pre = (ks < 23);
    float4 nx0, nx1;
    half8 nb0, nb1;
    if (pre) {
      const int k1 = (ks + 1) * 32;
      nx0 = *(const float4*)(Xp + k1);
      nx1 = *(const float4*)(Xp + k1 + 4);
      nb0 = *(const half8*)(BaP + k1);
      nb1 = *(const half8*)(BbP + k1);
    }
    half8 aAv[2], aBv[2], bAv[2], bBv[2];
#pragma unroll
    for (int f = 0; f < 2; ++f) {
      aAv[f] = *(const half8*)&Aa[cur][(arow + f * 16) * RS + kg];
      aBv[f] = *(const half8*)&Ab[cur][(arow + f * 16) * RS + kg];
      bAv[f] = *(const half8*)&Ba[cur][(brow + f * 16) * RS + kg];
      bBv[f] = *(const half8*)&Bb[cur][(brow + f * 16) * RS + kg];
    }
#pragma unroll
    for (int fm = 0; fm < 2; ++fm)
#pragma unroll
      for (int fn = 0; fn < 2; ++fn) {
        accM[fm][fn] = __builtin_amdgcn_mfma_f32_16x16x32_f16(aAv[fm], bAv[fn], accM[fm][fn], 0, 0, 0);
        accR[fm][fn] = __builtin_amdgcn_mfma_f32_16x16x32_f16(aBv[fm], bAv[fn], accR[fm][fn], 0, 0, 0);
        accR[fm][fn] = __builtin_amdgcn_mfma_f32_16x16x32_f16(aAv[fm], bBv[fn], accR[fm][fn], 0, 0, 0);
      }
    if (pre) {
      half8 hi, re;
      cvt8(nx0, nx1, hi, re);
      *(half8*)&Aa[nxt][woff] = hi;
      *(half8*)&Ab[nxt][woff] = re;
      *(half8*)&Ba[nxt][woff] = nb0;
      *(half8*)&Bb[nxt][woff] = nb1;
    }
    __syncthreads();
  }

  // epilogue: same layout/recombine/tanh as round 5
#pragma unroll
  for (int fm = 0; fm < 2; ++fm) {
    const int mb = rowBase + wm * 32 + fm * 16 + (lane >> 4) * 4;
#pragma unroll
    for (int fn = 0; fn < 2; ++fn) {
      const int n = colBase + wn * 32 + fn * 16 + (lane & 15);
      const float bv = bias[n];
#pragma unroll
      for (int r = 0; r < 4; ++r) {
        const float val = accM[fm][fn][r] * 0.015625f
                        + accR[fm][fn][r] * 3.814697265625e-6f + bv;
        C[(size_t)(mb + r) * D + n] = tanhf(val);
      }
    }
  }
}

// ---------------- Kernel B: Z = l2norm(H1 @ W2 + b2)  [M,D]x[D,E] ----------------
__global__ __launch_bounds__(256) void gemm2_norm(
    const float* __restrict__ H, const float* __restrict__ W2,
    const float* __restrict__ b2, float* __restrict__ Z)
{
  __shared__ float Hs[32 * 132];
  __shared__ float W2s[128 * 32];
  const int t = threadIdx.x;
  const int rowBase = blockIdx.x * 32;
  const int rl = t >> 3;
  const int n0 = (t & 7) * 4;

  float acc[4] = {0.f, 0.f, 0.f, 0.f};

  for (int kc = 0; kc < D; kc += 128) {
    __syncthreads();
    for (int i = t; i < 32 * 32; i += 256) {
      const int r = i >> 5, gq = i & 31;
      *(float4*)&Hs[r * 132 + gq * 4] =
          *(const float4*)&H[(size_t)(rowBase + r) * D + kc + gq * 4];
    }
    for (int i = t; i < 1024; i += 256)
      *(float4*)&W2s[i * 4] = *(const float4*)&W2[(size_t)kc * E + i * 4];
    __syncthreads();
#pragma unroll 4
    for (int k4 = 0; k4 < 32; ++k4) {
      float4 hv = *(const float4*)&Hs[rl * 132 + k4 * 4];
      const float h[4] = {hv.x, hv.y, hv.z, hv.w};
#pragma unroll
      for (int j = 0; j < 4; ++j) {
        float4 w = *(const float4*)&W2s[(k4 * 4 + j) * E + n0];
        acc[0] = fmaf(h[j], w.x, acc[0]); acc[1] = fmaf(h[j], w.y, acc[1]);
        acc[2] = fmaf(h[j], w.z, acc[2]); acc[3] = fmaf(h[j], w.w, acc[3]);
      }
    }
  }

  float4 bb = *(const float4*)&b2[n0];
  acc[0] += bb.x; acc[1] += bb.y; acc[2] += bb.z; acc[3] += bb.w;
  float ss = acc[0] * acc[0];
  ss += acc[1] * acc[1]; ss += acc[2] * acc[2]; ss += acc[3] * acc[3];
  ss += __shfl_xor(ss, 1, 8);
  ss += __shfl_xor(ss, 2, 8);
  ss += __shfl_xor(ss, 4, 8);
  const float inv = 1.0f / fmaxf(sqrtf(ss), 1e-12f);
  float4 zv = make_float4(acc[0] * inv, acc[1] * inv, acc[2] * inv, acc[3] * inv);
  *(float4*)&Z[(size_t)(rowBase + rl) * E + n0] = zv;
}

// ---------------- Kernel C: VQ argmin via MFMA + gather + STE + per-row loss ----------------
__global__ __launch_bounds__(512) void vq_mfma(
    const float* __restrict__ Z, const float* __restrict__ CB,
    const _Float16* __restrict__ CBh, const _Float16* __restrict__ CBr,
    const float* __restrict__ ccg, float* __restrict__ zq_out,
    float* __restrict__ idx_out, float* __restrict__ lossp)
{
  __shared__ float bDs[64][4];
  __shared__ int   bIs[64][4];

  const int t = threadIdx.x;
  const int lane = t & 63, wave = t >> 6;
  const int mh = wave & 1;
  const int cq = wave >> 1;
  const int rowBase = blockIdx.x * 64;
  const int col = lane & 15, kg = lane >> 4;

  half8 zh[2], zr[2];
#pragma unroll
  for (int mt = 0; mt < 2; ++mt) {
    const float* zp = Z + (size_t)(rowBase + mh * 32 + mt * 16 + col) * E + kg * 8;
    const float4 a = *(const float4*)zp;
    const float4 b = *(const float4*)(zp + 4);
    const float v[8] = {a.x, a.y, a.z, a.w, b.x, b.y, b.z, b.w};
#pragma unroll
    for (int e = 0; e < 8; ++e) {
      const _Float16 h = (_Float16)v[e];
      zh[mt][e] = h;
      zr[mt][e] = (_Float16)((v[e] - (float)h) * 4096.0f);
    }
  }

  const f32x4 zero4 = {0.f, 0.f, 0.f, 0.f};
  float best[2][4];
  int bi[2][4];
#pragma unroll
  for (int mt = 0; mt < 2; ++mt)
#pragma unroll
    for (int r = 0; r < 4; ++r) { best[mt][r] = 3.4e38f; bi[mt][r] = 0; }

  const _Float16* ph = CBh + ((size_t)(cq * 2048 + col) * E + kg * 8);
  const _Float16* pr = CBr + ((size_t)(cq * 2048 + col) * E + kg * 8);
  const float* pc = ccg + cq * 2048 + col;
  int curIdx = cq * 2048 + col;

  for (int tt = 0; tt < 128; ++tt) {
    const half8 bh = *(const half8*)ph;
    const half8 br = *(const half8*)pr;
    const float ccv = *pc;
    ph += 16 * E; pr += 16 * E; pc += 16;
#pragma unroll
    for (int mt = 0; mt < 2; ++mt) {
      f32x4 aM = __builtin_amdgcn_mfma_f32_16x16x32_f16(zh[mt], bh, zero4, 0, 0, 0);
      f32x4 aR = __builtin_amdgcn_mfma_f32_16x16x32_f16(zr[mt], bh, zero4, 0, 0, 0);
      aR = __builtin_amdgcn_mfma_f32_16x16x32_f16(zh[mt], br, aR, 0, 0, 0);
#pragma unroll
      for (int r = 0; r < 4; ++r) {
        const float u = fmaf(aR[r], 2.44140625e-4f, aM[r]);
        const float d = fmaf(u, -2.0f, ccv);
        if (d < best[mt][r]) { best[mt][r] = d; bi[mt][r] = curIdx; }
      }
    }
    curIdx += 16;
  }

#pragma unroll
  for (int m = 1; m <= 8; m <<= 1) {
#pragma unroll
    for (int mt = 0; mt < 2; ++mt)
#pragma unroll
      for (int r = 0; r < 4; ++r) {
        const float ob = __shfl_xor(best[mt][r], m, 64);
        const int   oi = __shfl_xor(bi[mt][r],   m, 64);
        if (ob < best[mt][r] || (ob == best[mt][r] && oi < bi[mt][r])) {
          best[mt][r] = ob; bi[mt][r] = oi;
        }
      }
  }

  if (col == 0) {
#pragma unroll
    for (int mt = 0; mt < 2; ++mt)
#pragma unroll
      for (int r = 0; r < 4; ++r) {
        const int rl = mh * 32 + mt * 16 + kg * 4 + r;
        bDs[rl][cq] = best[mt][r];
        bIs[rl][cq] = bi[mt][r];
      }
  }
  __syncthreads();

  const int rl = t >> 3, part = t & 7;
  float bd = bDs[rl][0];
  int bidx = bIs[rl][0];
#pragma unroll
  for (int q = 1; q < 4; ++q)
    if (bDs[rl][q] < bd) { bd = bDs[rl][q]; bidx = bIs[rl][q]; }

  const int row = rowBase + rl;
  const float4 c4 = *(const float4*)&CB[(size_t)bidx * E + part * 4];
  const float4 z4 = *(const float4*)&Z[(size_t)row * E + part * 4];
  const float dx = c4.x - z4.x, dy = c4.y - z4.y;
  const float dz = c4.z - z4.z, dw = c4.w - z4.w;
  *(float4*)&zq_out[(size_t)row * E + part * 4] =
      make_float4(z4.x + dx, z4.y + dy, z4.z + dz, z4.w + dw);
  float ls = dx * dx;
  ls += dy * dy; ls += dz * dz; ls += dw * dw;
  ls += __shfl_xor(ls, 1, 8);
  ls += __shfl_xor(ls, 2, 8);
  ls += __shfl_xor(ls, 4, 8);
  if (part == 0) {
    lossp[row] = ls;
    idx_out[row] = (float)bidx;
  }
}

// ---------------- Kernel D: loss = sum(lossp) / (M*E) ----------------
__global__ __launch_bounds__(256) void loss_reduce(const float* __restrict__ lossp, float* __restrict__ out)
{
  float s = 0.f;
  const float4* p = reinterpret_cast<const float4*>(lossp);
  for (int i = threadIdx.x; i < M / 4; i += 256) {
    float4 v = p[i];
    s += v.x + v.y + v.z + v.w;
  }
#pragma unroll
  for (int m = 32; m >= 1; m >>= 1) s += __shfl_xor(s, m, 64);
  __shared__ float red[4];
  if ((threadIdx.x & 63) == 0) red[threadIdx.x >> 6] = s;
  __syncthreads();
  if (threadIdx.x == 0)
    out[0] = (red[0] + red[1] + red[2] + red[3]) * (1.0f / (float)(M * E));
}

extern "C" void kernel_launch(void* const* d_in, const int* in_sizes, int n_in,
                              void* d_out, int out_size, void* d_ws, size_t ws_size,
                              hipStream_t stream)
{
  const float* X  = (const float*)d_in[0];
  const float* W1 = (const float*)d_in[1];
  const float* b1 = (const float*)d_in[2];
  const float* W2 = (const float*)d_in[3];
  const float* b2 = (const float*)d_in[4];
  const float* CB = (const float*)d_in[5];

  float* out  = (float*)d_out;
  float* zq   = out;
  float* loss = out + 524288;
  float* idxf = out + 524289;

  char* ws = (char*)d_ws;
  float* H1 = (float*)ws;                                  // 48 MB
  float* Z  = (float*)(ws + (size_t)M * D * 4);            // 2 MB
  float* cc = Z + (size_t)M * E;                           // 32 KB
  float* lp = cc + K;                                      // 64 KB
  _Float16* W1aT = (_Float16*)(lp + M);                    // 1.125 MB
  _Float16* W1bT = W1aT + (size_t)D * D;                   // 1.125 MB
  _Float16* CBh  = W1bT + (size_t)D * D;                   // 512 KB
  _Float16* CBr  = CBh + (size_t)K * E;                    // 512 KB

  split_w1t<<<dim3(D / 32, D / 32), 256, 0, stream>>>(W1, W1aT, W1bT);
  cb_prep<<<dim3(K / 256), 256, 0, stream>>>(CB, cc, CBh, CBr);
  gemm1_mfma<<<dim3(M / 64, D / 64), 256, 0, stream>>>(X, W1aT, W1bT, b1, H1);
  gemm2_norm<<<dim3(M / 32), 256, 0, stream>>>(H1, W2, b2, Z);
  vq_mfma<<<dim3(M / 64), 512, 0, stream>>>(Z, CB, CBh, CBr, cc, zq, idxf, lp);
  loss_reduce<<<1, 256, 0, stream>>>(lp, loss);
}